// Round 9
// baseline (291.778 us; speedup 1.0000x reference)
//
#include <hip/hip_runtime.h>
#include <stdint.h>

#define VOCAB 28996
#define EMBED 512
#define NROWS 8192
#define VPAD2 29184  /* 114 * 256 */
#define LOG2E 1.4426950408889634f
#define WSCALE 16.0f
#define INV_WSCALE_L2E (LOG2E / 16.0f)

typedef __attribute__((ext_vector_type(4)))  int   i32x4;
typedef __attribute__((ext_vector_type(8)))  int   i32x8;
typedef __attribute__((ext_vector_type(16))) float f32x16;

// pack 4 floats -> 4 x fp8 e4m3 (OCP, RNE, saturating) in one i32
__device__ __forceinline__ int pk_fp8x4(float a, float b, float c, float d) {
  int r = __builtin_amdgcn_cvt_pk_fp8_f32(a, b, 0, false);
  r = __builtin_amdgcn_cvt_pk_fp8_f32(c, d, r, true);
  return r;
}

// Fragment-major tiled layout (R8-proven): tile T[g][s] (g = 32-row group,
// s = 64-k step) is 2048 B; lane lam = h*32 + (row&31) holds row's k-bytes
// [s*64 + h*32, +32) at T + lam*32. A wave's fragment load is one contiguous
// 2 KB burst — no LDS, no barriers in the GEMM.

// ---- fused prep (coalesced): W*16 -> fp8 tiles (pad VPAD2), x -> fp8 tiles,
//      p_y, zero sg. Each cvt thread WRITES 16 contiguous tile bytes and
//      READS 64 contiguous bytes of the source row (full-cacheline segments).
// blocks [0,3648):    W tiles  (29184*512/16/256 = 3648)
// blocks [3648,4672): x tiles  (8192*512/16/256 = 1024)
// blocks [4672,6720): py (1 wave/row, 4 rows/block)
// blocks [6720,6752): zero sg
__global__ void __launch_bounds__(256)
prep_kernel(const float* __restrict__ x, const float* __restrict__ W,
            const float* __restrict__ b, const int* __restrict__ y,
            uint8_t* __restrict__ xT, uint8_t* __restrict__ wT,
            float* __restrict__ py, float* __restrict__ sg) {
  const int bid = blockIdx.x;
  if (bid < 4672) {                        // ---- tile conversions ----
    const bool isW = bid < 3648;
    const size_t beta = ((size_t)(isW ? bid : bid - 3648) * 256 + threadIdx.x) * 16;
    const int tileIdx = (int)(beta >> 11);
    const int om  = (int)(beta & 2047);
    const int g = tileIdx >> 3, s = tileIdx & 7;
    const int lam = om >> 5, c0 = om & 31;       // c0 in {0,16}
    const int row = g * 32 + (lam & 31);
    const int k0  = s * 64 + (lam >> 5) * 32 + c0;  // float index in row
    int4 o;
    if (isW) {
      if (row < VOCAB) {
        const float4* src = (const float4*)(W + (size_t)row * EMBED + k0);
        float4 v0 = src[0], v1 = src[1], v2 = src[2], v3 = src[3];
        o.x = pk_fp8x4(v0.x * WSCALE, v0.y * WSCALE, v0.z * WSCALE, v0.w * WSCALE);
        o.y = pk_fp8x4(v1.x * WSCALE, v1.y * WSCALE, v1.z * WSCALE, v1.w * WSCALE);
        o.z = pk_fp8x4(v2.x * WSCALE, v2.y * WSCALE, v2.z * WSCALE, v2.w * WSCALE);
        o.w = pk_fp8x4(v3.x * WSCALE, v3.y * WSCALE, v3.z * WSCALE, v3.w * WSCALE);
      } else { o.x = 0; o.y = 0; o.z = 0; o.w = 0; }
      *(int4*)(wT + beta) = o;
    } else {
      const float4* src = (const float4*)(x + (size_t)row * EMBED + k0);
      float4 v0 = src[0], v1 = src[1], v2 = src[2], v3 = src[3];
      o.x = pk_fp8x4(v0.x, v0.y, v0.z, v0.w);
      o.y = pk_fp8x4(v1.x, v1.y, v1.z, v1.w);
      o.z = pk_fp8x4(v2.x, v2.y, v2.z, v2.w);
      o.w = pk_fp8x4(v3.x, v3.y, v3.z, v3.w);
      *(int4*)(xT + beta) = o;
    }
  } else if (bid < 6720) {                 // ---- py: e^{x.W[y]+b[y]}, fp32 exact ----
    const int row  = ((bid - 4672) * 256 + threadIdx.x) >> 6;
    const int lane = threadIdx.x & 63;
    const int yr = y[row];
    const float4* xr = (const float4*)(x + (size_t)row * EMBED);
    const float4* wr = (const float4*)(W + (size_t)yr * EMBED);
    float d = 0.f;
#pragma unroll
    for (int t = 0; t < 2; ++t) {
      float4 a = xr[lane * 2 + t], c = wr[lane * 2 + t];
      d += a.x * c.x + a.y * c.y + a.z * c.z + a.w * c.w;
    }
#pragma unroll
    for (int m = 1; m < 64; m <<= 1) d += __shfl_xor(d, m);
    if (lane == 0) py[row] = __expf(d + b[yr]);
  } else {                                 // ---- zero sg ----
    int i = (bid - 6720) * 256 + threadIdx.x;
    sg[i] = 0.f;
  }
}

// ---- fused GEMM (16*logits = x . (16W)^T, MX-fp8 32x32x64) + row-sum exp ----
// NO LDS, NO barriers. Block tile 128x256 via 4 waves (2x2 of 64x128 wave
// tiles). Each wave: acc 2x4 of 32x32 (128 AGPRs), reads A 2 slabs + B 4
// slabs per k-step = 96 KB / 8.4 MFLOP = 87 FLOP/byte (vs 64 at 64x64) —
// cuts chip L2 operand traffic 3.72 -> 2.80 GB.
__global__ void __launch_bounds__(256, 2)
gemm_stats_kernel(const uint8_t* __restrict__ xT, const uint8_t* __restrict__ wT,
                  const float* __restrict__ bias, float* __restrict__ sg) {
  const int tid  = threadIdx.x;
  const int lane = tid & 63;
  const int w    = tid >> 6;        // wave 0..3
  const int l31  = lane & 31;
  const int h    = lane >> 5;       // k-half within a 64-k step
  const int wr   = (w >> 1) * 64;   // wave row offset in block tile
  const int wc   = (w & 1) * 128;   // wave col offset in block tile
  const int rowBase = blockIdx.x * 128;  // x rows (grid.x = 64, fast dim)
  const int colBase = blockIdx.y * 256;  // vocab cols (grid.y = 114)

  const uint8_t* aT = xT + ((size_t)(((rowBase + wr) >> 5) * 8)) * 2048 + lane * 32;
  const uint8_t* bT = wT + ((size_t)(((colBase + wc) >> 5) * 8)) * 2048 + lane * 32;

  f32x16 acc[2][4];
#pragma unroll
  for (int i = 0; i < 2; ++i)
#pragma unroll
    for (int j = 0; j < 4; ++j)
#pragma unroll
      for (int r = 0; r < 16; ++r) acc[i][j][r] = 0.f;

#pragma unroll
  for (int s = 0; s < 8; ++s) {
    const int offs = s * 2048;
    i32x8 af[2], bq[4];
#pragma unroll
    for (int ii = 0; ii < 2; ++ii) {
      i32x4 lo = *(const i32x4*)(aT + ii * 16384 + offs);
      i32x4 hi = *(const i32x4*)(aT + ii * 16384 + offs + 16);
      af[ii] = __builtin_shufflevector(lo, hi, 0, 1, 2, 3, 4, 5, 6, 7);
    }
#pragma unroll
    for (int jj = 0; jj < 4; ++jj) {
      i32x4 lo = *(const i32x4*)(bT + jj * 16384 + offs);
      i32x4 hi = *(const i32x4*)(bT + jj * 16384 + offs + 16);
      bq[jj] = __builtin_shufflevector(lo, hi, 0, 1, 2, 3, 4, 5, 6, 7);
    }
#pragma unroll
    for (int ii = 0; ii < 2; ++ii)
#pragma unroll
      for (int jj = 0; jj < 4; ++jj)
        acc[ii][jj] = __builtin_amdgcn_mfma_scale_f32_32x32x64_f8f6f4(
            af[ii], bq[jj], acc[ii][jj], 0, 0, 0, 0x7F7F7F7F, 0, 0x7F7F7F7F);
  }

  // ---- epilogue: s_row += sum_j exp(acc/16 + bias) ----
  // 32x32 C/D layout (m74/m101): col = lane&31, row = (reg&3)+8*(reg>>2)+4*h
  float bvl[4];
#pragma unroll
  for (int jj = 0; jj < 4; ++jj) {
    const int col = colBase + wc + jj * 32 + l31;
    bvl[jj] = (col < VOCAB) ? bias[col] * LOG2E : -1e30f;
  }

  float sp[32];  // v = ii*16 + reg
#pragma unroll
  for (int ii = 0; ii < 2; ++ii)
#pragma unroll
    for (int r = 0; r < 16; ++r) {
      float e = 0.f;
#pragma unroll
      for (int jj = 0; jj < 4; ++jj)
        e += exp2f(fmaf(acc[ii][jj][r], INV_WSCALE_L2E, bvl[jj]));
      sp[ii * 16 + r] = e;
    }

  // stacking reduction over the 32 cols (xor 1..16 stays within the h-half);
  // ends with lane holding the full col-sum for value index v == (lane&31).
  float t1[16];
#pragma unroll
  for (int u = 0; u < 16; ++u) {
    float a = sp[2 * u]     + __shfl_xor(sp[2 * u],     1);
    float b = sp[2 * u + 1] + __shfl_xor(sp[2 * u + 1], 1);
    t1[u] = (l31 & 1) ? b : a;
  }
  float t2[8];
#pragma unroll
  for (int u = 0; u < 8; ++u) {
    float a = t1[2 * u]     + __shfl_xor(t1[2 * u],     2);
    float b = t1[2 * u + 1] + __shfl_xor(t1[2 * u + 1], 2);
    t2[u] = (l31 & 2) ? b : a;
  }
  float t3[4];
#pragma unroll
  for (int u = 0; u < 4; ++u) {
    float a = t2[2 * u]     + __shfl_xor(t2[2 * u],     4);
    float b = t2[2 * u + 1] + __shfl_xor(t2[2 * u + 1], 4);
    t3[u] = (l31 & 4) ? b : a;
  }
  float t4[2];
#pragma unroll
  for (int u = 0; u < 2; ++u) {
    float a = t3[2 * u]     + __shfl_xor(t3[2 * u],     8);
    float b = t3[2 * u + 1] + __shfl_xor(t3[2 * u + 1], 8);
    t4[u] = (l31 & 8) ? b : a;
  }
  {
    float a = t4[0] + __shfl_xor(t4[0], 16);
    float b = t4[1] + __shfl_xor(t4[1], 16);
    float ssum = (l31 & 16) ? b : a;
    const int v = l31;                 // ii = v>>4, reg = v&15
    const int row = rowBase + wr + (v >> 4) * 32 + (v & 3) + 8 * ((v & 15) >> 2) + 4 * h;
    atomicAdd(&sg[row], ssum);
  }
}

// ---- final: loss = log(V+1) - mean(py/s)  (q-term ~7e-10, dropped) ----
__global__ void finalize_kernel(const float* __restrict__ sg, const float* __restrict__ py,
                                float* __restrict__ out) {
  __shared__ float red[256];
  float a = 0.f;
  for (int i = threadIdx.x; i < NROWS; i += 256)
    a += py[i] / sg[i];
  red[threadIdx.x] = a;
  __syncthreads();
  for (int st = 128; st > 0; st >>= 1) {
    if (threadIdx.x < st) red[threadIdx.x] += red[threadIdx.x + st];
    __syncthreads();
  }
  if (threadIdx.x == 0)
    out[0] = logf((float)(VOCAB + 1)) - red[0] * (1.f / (float)NROWS);
}

extern "C" void kernel_launch(void* const* d_in, const int* in_sizes, int n_in,
                              void* d_out, int out_size, void* d_ws, size_t ws_size,
                              hipStream_t stream) {
  const float* x = (const float*)d_in[0];
  const int*   y = (const int*)d_in[1];
  const float* W = (const float*)d_in[2];
  const float* b = (const float*)d_in[3];

  char* ws = (char*)d_ws;
  uint8_t* xT = (uint8_t*)ws;                             // 4,194,304 B
  uint8_t* wT = (uint8_t*)(ws + 4194304);                 // 14,942,208 B
  float*   sg = (float*)(ws + 4194304 + 14942208);        // 32 KiB
  float*   py = sg + NROWS;                               // 32 KiB

  prep_kernel<<<6752, 256, 0, stream>>>(x, W, b, y, xT, wT, py, sg);
  gemm_stats_kernel<<<dim3(64, 114), 256, 0, stream>>>(xT, wT, b, sg);
  finalize_kernel<<<1, 256, 0, stream>>>(sg, py, (float*)d_out);
}

// Round 10
// 275.387 us; speedup vs baseline: 1.0595x; 1.0595x over previous
//
#include <hip/hip_runtime.h>
#include <stdint.h>

#define VOCAB 28996
#define EMBED 512
#define NROWS 8192
#define VPAD2 29184  /* 114 * 256 */
#define LOG2E 1.4426950408889634f
#define WSCALE 16.0f
#define INV_WSCALE_L2E (LOG2E / 16.0f)

typedef __attribute__((ext_vector_type(4)))  int   i32x4;
typedef __attribute__((ext_vector_type(8)))  int   i32x8;
typedef __attribute__((ext_vector_type(16))) float f32x16;

// pack 4 floats -> 4 x fp8 e4m3 (OCP, RNE, saturating) in one i32
__device__ __forceinline__ int pk_fp8x4(float a, float b, float c, float d) {
  int r = __builtin_amdgcn_cvt_pk_fp8_f32(a, b, 0, false);
  r = __builtin_amdgcn_cvt_pk_fp8_f32(c, d, r, true);
  return r;
}

// Fragment-major tiled layout (R8-proven): tile T[g][s] (g = 32-row group,
// s = 64-k step) is 2048 B; lane lam = h*32 + (row&31) holds row's k-bytes
// [s*64 + h*32, +32) at T + lam*32. A wave's fragment load is one contiguous
// 2 KB burst — no LDS, no barriers in the GEMM.

// ---- fused prep (coalesced, R9-proven): W*16 -> fp8 tiles (pad VPAD2),
//      x -> fp8 tiles, p_y, zero sg. Each cvt thread writes 16 contiguous
//      tile bytes, reads 64 contiguous source bytes.
// blocks [0,3648):    W tiles  (29184*512/16/256 = 3648)
// blocks [3648,4672): x tiles  (8192*512/16/256 = 1024)
// blocks [4672,6720): py (1 wave/row, 4 rows/block)
// blocks [6720,6752): zero sg
__global__ void __launch_bounds__(256)
prep_kernel(const float* __restrict__ x, const float* __restrict__ W,
            const float* __restrict__ b, const int* __restrict__ y,
            uint8_t* __restrict__ xT, uint8_t* __restrict__ wT,
            float* __restrict__ py, float* __restrict__ sg) {
  const int bid = blockIdx.x;
  if (bid < 4672) {                        // ---- tile conversions ----
    const bool isW = bid < 3648;
    const size_t beta = ((size_t)(isW ? bid : bid - 3648) * 256 + threadIdx.x) * 16;
    const int tileIdx = (int)(beta >> 11);
    const int om  = (int)(beta & 2047);
    const int g = tileIdx >> 3, s = tileIdx & 7;
    const int lam = om >> 5, c0 = om & 31;       // c0 in {0,16}
    const int row = g * 32 + (lam & 31);
    const int k0  = s * 64 + (lam >> 5) * 32 + c0;  // float index in row
    int4 o;
    if (isW) {
      if (row < VOCAB) {
        const float4* src = (const float4*)(W + (size_t)row * EMBED + k0);
        float4 v0 = src[0], v1 = src[1], v2 = src[2], v3 = src[3];
        o.x = pk_fp8x4(v0.x * WSCALE, v0.y * WSCALE, v0.z * WSCALE, v0.w * WSCALE);
        o.y = pk_fp8x4(v1.x * WSCALE, v1.y * WSCALE, v1.z * WSCALE, v1.w * WSCALE);
        o.z = pk_fp8x4(v2.x * WSCALE, v2.y * WSCALE, v2.z * WSCALE, v2.w * WSCALE);
        o.w = pk_fp8x4(v3.x * WSCALE, v3.y * WSCALE, v3.z * WSCALE, v3.w * WSCALE);
      } else { o.x = 0; o.y = 0; o.z = 0; o.w = 0; }
      *(int4*)(wT + beta) = o;
    } else {
      const float4* src = (const float4*)(x + (size_t)row * EMBED + k0);
      float4 v0 = src[0], v1 = src[1], v2 = src[2], v3 = src[3];
      o.x = pk_fp8x4(v0.x, v0.y, v0.z, v0.w);
      o.y = pk_fp8x4(v1.x, v1.y, v1.z, v1.w);
      o.z = pk_fp8x4(v2.x, v2.y, v2.z, v2.w);
      o.w = pk_fp8x4(v3.x, v3.y, v3.z, v3.w);
      *(int4*)(xT + beta) = o;
    }
  } else if (bid < 6720) {                 // ---- py: e^{x.W[y]+b[y]}, fp32 exact ----
    const int row  = ((bid - 4672) * 256 + threadIdx.x) >> 6;
    const int lane = threadIdx.x & 63;
    const int yr = y[row];
    const float4* xr = (const float4*)(x + (size_t)row * EMBED);
    const float4* wr = (const float4*)(W + (size_t)yr * EMBED);
    float d = 0.f;
#pragma unroll
    for (int t = 0; t < 2; ++t) {
      float4 a = xr[lane * 2 + t], c = wr[lane * 2 + t];
      d += a.x * c.x + a.y * c.y + a.z * c.z + a.w * c.w;
    }
#pragma unroll
    for (int m = 1; m < 64; m <<= 1) d += __shfl_xor(d, m);
    if (lane == 0) py[row] = __expf(d + b[yr]);
  } else {                                 // ---- zero sg ----
    int i = (bid - 6720) * 256 + threadIdx.x;
    sg[i] = 0.f;
  }
}

// ---- fused GEMM (16*logits = x . (16W)^T, MX-fp8 32x32x64) + row-sum exp ----
// NO LDS, NO barriers. Block tile 128x256 via 4 waves (2x2 of 64x128 wave
// tiles, acc 2x4 of 32x32 = 128 AGPRs, 85 FLOP/byte). Register-pressure
// control vs R9's spills: #pragma unroll 1 K-loop with explicit one-step
// lookahead (load s+1, MFMA s, rotate) — peak live ~48+48 arch + 128 acc,
// fits the 256-reg unified budget of launch_bounds(256,2).
__global__ void __launch_bounds__(256, 2)
gemm_stats_kernel(const uint8_t* __restrict__ xT, const uint8_t* __restrict__ wT,
                  const float* __restrict__ bias, float* __restrict__ sg) {
  const int tid  = threadIdx.x;
  const int lane = tid & 63;
  const int w    = tid >> 6;        // wave 0..3
  const int l31  = lane & 31;
  const int h    = lane >> 5;       // k-half within a 64-k step
  const int wr   = (w >> 1) * 64;   // wave row offset in block tile
  const int wc   = (w & 1) * 128;   // wave col offset in block tile
  const int rowBase = blockIdx.x * 128;  // x rows (grid.x = 64, fast dim)
  const int colBase = blockIdx.y * 256;  // vocab cols (grid.y = 114)

  const uint8_t* aT = xT + ((size_t)(((rowBase + wr) >> 5) * 8)) * 2048 + lane * 32;
  const uint8_t* bT = wT + ((size_t)(((colBase + wc) >> 5) * 8)) * 2048 + lane * 32;

  f32x16 acc[2][4];
#pragma unroll
  for (int i = 0; i < 2; ++i)
#pragma unroll
    for (int j = 0; j < 4; ++j)
#pragma unroll
      for (int r = 0; r < 16; ++r) acc[i][j][r] = 0.f;

  auto ldfrag = [](const uint8_t* p) -> i32x8 {
    i32x4 lo = *(const i32x4*)p;
    i32x4 hi = *(const i32x4*)(p + 16);
    return __builtin_shufflevector(lo, hi, 0, 1, 2, 3, 4, 5, 6, 7);
  };

  i32x8 af[2], bq[4];
#pragma unroll
  for (int ii = 0; ii < 2; ++ii) af[ii] = ldfrag(aT + ii * 16384);
#pragma unroll
  for (int jj = 0; jj < 4; ++jj) bq[jj] = ldfrag(bT + jj * 16384);

#pragma unroll 1
  for (int s = 0; s < 7; ++s) {
    const int offn = (s + 1) * 2048;
    i32x8 naf[2], nbq[4];
#pragma unroll
    for (int ii = 0; ii < 2; ++ii) naf[ii] = ldfrag(aT + ii * 16384 + offn);
#pragma unroll
    for (int jj = 0; jj < 4; ++jj) nbq[jj] = ldfrag(bT + jj * 16384 + offn);
#pragma unroll
    for (int ii = 0; ii < 2; ++ii)
#pragma unroll
      for (int jj = 0; jj < 4; ++jj)
        acc[ii][jj] = __builtin_amdgcn_mfma_scale_f32_32x32x64_f8f6f4(
            af[ii], bq[jj], acc[ii][jj], 0, 0, 0, 0x7F7F7F7F, 0, 0x7F7F7F7F);
#pragma unroll
    for (int ii = 0; ii < 2; ++ii) af[ii] = naf[ii];
#pragma unroll
    for (int jj = 0; jj < 4; ++jj) bq[jj] = nbq[jj];
  }
#pragma unroll
  for (int ii = 0; ii < 2; ++ii)
#pragma unroll
    for (int jj = 0; jj < 4; ++jj)
      acc[ii][jj] = __builtin_amdgcn_mfma_scale_f32_32x32x64_f8f6f4(
          af[ii], bq[jj], acc[ii][jj], 0, 0, 0, 0x7F7F7F7F, 0, 0x7F7F7F7F);

  // ---- epilogue: s_row += sum_j exp(acc/16 + bias) ----
  // 32x32 C/D layout (m74/m101): col = lane&31, row = (reg&3)+8*(reg>>2)+4*h
  float bvl[4];
#pragma unroll
  for (int jj = 0; jj < 4; ++jj) {
    const int col = colBase + wc + jj * 32 + l31;
    bvl[jj] = (col < VOCAB) ? bias[col] * LOG2E : -1e30f;
  }

  float sp[32];  // v = ii*16 + reg
#pragma unroll
  for (int ii = 0; ii < 2; ++ii)
#pragma unroll
    for (int r = 0; r < 16; ++r) {
      float e = 0.f;
#pragma unroll
      for (int jj = 0; jj < 4; ++jj)
        e += exp2f(fmaf(acc[ii][jj][r], INV_WSCALE_L2E, bvl[jj]));
      sp[ii * 16 + r] = e;
    }

  // stacking reduction over the 32 cols (xor 1..16 stays within the h-half);
  // ends with lane holding the full col-sum for value index v == (lane&31).
  float t1[16];
#pragma unroll
  for (int u = 0; u < 16; ++u) {
    float a = sp[2 * u]     + __shfl_xor(sp[2 * u],     1);
    float b = sp[2 * u + 1] + __shfl_xor(sp[2 * u + 1], 1);
    t1[u] = (l31 & 1) ? b : a;
  }
  float t2[8];
#pragma unroll
  for (int u = 0; u < 8; ++u) {
    float a = t1[2 * u]     + __shfl_xor(t1[2 * u],     2);
    float b = t1[2 * u + 1] + __shfl_xor(t1[2 * u + 1], 2);
    t2[u] = (l31 & 2) ? b : a;
  }
  float t3[4];
#pragma unroll
  for (int u = 0; u < 4; ++u) {
    float a = t2[2 * u]     + __shfl_xor(t2[2 * u],     4);
    float b = t2[2 * u + 1] + __shfl_xor(t2[2 * u + 1], 4);
    t3[u] = (l31 & 4) ? b : a;
  }
  float t4[2];
#pragma unroll
  for (int u = 0; u < 2; ++u) {
    float a = t3[2 * u]     + __shfl_xor(t3[2 * u],     8);
    float b = t3[2 * u + 1] + __shfl_xor(t3[2 * u + 1], 8);
    t4[u] = (l31 & 8) ? b : a;
  }
  {
    float a = t4[0] + __shfl_xor(t4[0], 16);
    float b = t4[1] + __shfl_xor(t4[1], 16);
    float ssum = (l31 & 16) ? b : a;
    const int v = l31;                 // ii = v>>4, reg = v&15
    const int row = rowBase + wr + (v >> 4) * 32 + (v & 3) + 8 * ((v & 15) >> 2) + 4 * h;
    atomicAdd(&sg[row], ssum);
  }
}

// ---- final: loss = log(V+1) - mean(py/s)  (q-term ~7e-10, dropped) ----
__global__ void finalize_kernel(const float* __restrict__ sg, const float* __restrict__ py,
                                float* __restrict__ out) {
  __shared__ float red[256];
  float a = 0.f;
  for (int i = threadIdx.x; i < NROWS; i += 256)
    a += py[i] / sg[i];
  red[threadIdx.x] = a;
  __syncthreads();
  for (int st = 128; st > 0; st >>= 1) {
    if (threadIdx.x < st) red[threadIdx.x] += red[threadIdx.x + st];
    __syncthreads();
  }
  if (threadIdx.x == 0)
    out[0] = logf((float)(VOCAB + 1)) - red[0] * (1.f / (float)NROWS);
}

extern "C" void kernel_launch(void* const* d_in, const int* in_sizes, int n_in,
                              void* d_out, int out_size, void* d_ws, size_t ws_size,
                              hipStream_t stream) {
  const float* x = (const float*)d_in[0];
  const int*   y = (const int*)d_in[1];
  const float* W = (const float*)d_in[2];
  const float* b = (const float*)d_in[3];

  char* ws = (char*)d_ws;
  uint8_t* xT = (uint8_t*)ws;                             // 4,194,304 B
  uint8_t* wT = (uint8_t*)(ws + 4194304);                 // 14,942,208 B
  float*   sg = (float*)(ws + 4194304 + 14942208);        // 32 KiB
  float*   py = sg + NROWS;                               // 32 KiB

  prep_kernel<<<6752, 256, 0, stream>>>(x, W, b, y, xT, wT, py, sg);
  gemm_stats_kernel<<<dim3(64, 114), 256, 0, stream>>>(xT, wT, b, sg);
  finalize_kernel<<<1, 256, 0, stream>>>(sg, py, (float*)d_out);
}